// Round 1
// 980.702 us; speedup vs baseline: 1.0899x; 1.0899x over previous
//
#include <hip/hip_runtime.h>

#define FS 11
#define HFS 5

constexpr int Bn = 8, Cn = 19, Hn = 512, Wn = 512;
constexpr int HWn = Hn * Wn;            // 262144
constexpr int CHWn = Cn * HWn;          // 4980736
constexpr int TOTn = Bn * CHWn;         // 39845888 (fits int)

// fused tile params
constexpr int TH = 32, TW = 64;
constexpr int HR  = TH + 10;            // 42 halo rows (h0-5 .. h0+36)
constexpr int HC4 = 20;                 // 80 halo cols = 20 float4 (w0-8 .. w0+71)
constexpr int NP4 = HR * HC4;           // 840 float4 halo pixels
constexpr int QS  = 84;                 // srinv/qs row stride (floats); 84%32=20 -> staggered banks
constexpr int WSS = 68;                 // ws row stride; 68%32=4 -> staggered banks

// taps[b][dim][j]: dim0 = kh (H-direction), dim1 = kw (W-direction, scaled by weight)
__global__ void k_taps(const float* __restrict__ spacing,
                       const float* __restrict__ inv_theta,
                       const float* __restrict__ wgt,
                       float* __restrict__ taps) {
    int t = threadIdx.x;
    if (t < Bn * 2 * FS) {
        int j = t % FS;
        int dim = (t / FS) & 1;
        int b = t / (2 * FS);
        float d = spacing[b * 2 + dim] * (float)(j - HFS);
        float a = d * inv_theta[dim];
        float k = __expf(-0.5f * a * a);
        if (j == HFS) k = 0.0f;          // message passing excludes self
        if (dim == 1) k *= wgt[0];       // fold smoothness_weight into kw
        taps[t] = k;
    }
}

// One block = one (b, 32x64 spatial tile), all 19 channels.
// Fuses: softmax (no max-sub; inputs bounded so exp can't overflow) + convH + convW + x0-add.
// LDS: srinv[42][84] (1/sum-exp per halo pixel), qs[42][84] (q for current channel),
//      ws[42][68] (convW intermediate). Total 39648 B -> 4 blocks/CU.
__global__ __launch_bounds__(256, 4) void k_fused(const float* __restrict__ xin,
                                                  const float* __restrict__ x0,
                                                  float* __restrict__ xout,
                                                  const float* __restrict__ taps) {
    __shared__ float srinv[HR * QS];     // 14112 B
    __shared__ float qs[HR * QS];        // 14112 B
    __shared__ float ws[HR * WSS];       // 11424 B

    const int tid = threadIdx.x;
    const int w0 = blockIdx.x * TW;
    const int h0 = blockIdx.y * TH;
    const int b  = blockIdx.z;

    const float* tp = taps + b * (2 * FS);
    float kh[FS], kw[FS];
#pragma unroll
    for (int j = 0; j < FS; j++) { kh[j] = tp[j]; kw[j] = tp[FS + j]; }

    const float* xb = xin + b * CHWn;

    // ---- pass 1: sum of exp over all channels at every halo pixel -> 1/sum in LDS ----
#pragma unroll 1
    for (int k = 0; k < 4; ++k) {
        int i = tid + 256 * k;
        if (i >= NP4) break;
        int r  = i / HC4, c4 = i % HC4;
        int hh = h0 - 5 + r;
        int ww = w0 - 8 + 4 * c4;
        if (hh >= 0 && hh < Hn && ww >= 0 && ww <= Wn - 4) {
            const float* p = xb + hh * Wn + ww;
            float4 s = {0.f, 0.f, 0.f, 0.f};
#pragma unroll
            for (int c = 0; c < Cn; ++c) {
                float4 v = *(const float4*)(p + c * HWn);
                s.x += __expf(v.x); s.y += __expf(v.y);
                s.z += __expf(v.z); s.w += __expf(v.w);
            }
            float4 rv = {1.f / s.x, 1.f / s.y, 1.f / s.z, 1.f / s.w};
            *(float4*)&srinv[r * QS + 4 * c4] = rv;
        }
    }
    __syncthreads();

    // ---- per channel: stage q -> convW -> convH + epilogue ----
    for (int c = 0; c < Cn; ++c) {
        const float* xc = xb + c * HWn;

        // stage q = exp(x) * rinv into qs (zeros outside image = zero-pad semantics)
#pragma unroll 1
        for (int k = 0; k < 4; ++k) {
            int i = tid + 256 * k;
            if (i >= NP4) break;
            int r  = i / HC4, c4 = i % HC4;
            int hh = h0 - 5 + r;
            int ww = w0 - 8 + 4 * c4;
            float4 qv = {0.f, 0.f, 0.f, 0.f};
            if (hh >= 0 && hh < Hn && ww >= 0 && ww <= Wn - 4) {
                float4 v  = *(const float4*)(xc + hh * Wn + ww);
                float4 rv = *(const float4*)&srinv[r * QS + 4 * c4];
                qv.x = __expf(v.x) * rv.x; qv.y = __expf(v.y) * rv.y;
                qv.z = __expf(v.z) * rv.z; qv.w = __expf(v.w) * rv.w;
            }
            *(float4*)&qs[r * QS + 4 * c4] = qv;
        }
        __syncthreads();

        // phase A: convW for all 42 halo rows; task = (row r, 8-col group g)
#pragma unroll 1
        for (int i = tid; i < HR * 8; i += 256) {
            int r = i >> 3, g = i & 7;
            float t[24];                 // qs f32 idx 8g .. 8g+23 (covers out cols 8g..8g+7 window)
#pragma unroll
            for (int m = 0; m < 6; ++m)
                *(float4*)&t[4 * m] = *(const float4*)&qs[r * QS + 8 * g + 4 * m];
            float o[8];
#pragma unroll
            for (int k2 = 0; k2 < 8; ++k2) {
                float a = 0.f;
#pragma unroll
                for (int j = 0; j < FS; ++j) {
                    if (j == HFS) continue;     // center tap zero
                    a = fmaf(kw[j], t[k2 + 3 + j], a);
                }
                o[k2] = a;
            }
            float4 oa = {o[0], o[1], o[2], o[3]};
            float4 ob = {o[4], o[5], o[6], o[7]};
            *(float4*)&ws[r * WSS + 8 * g]     = oa;
            *(float4*)&ws[r * WSS + 8 * g + 4] = ob;
        }
        __syncthreads();

        // phase B: convH (2 rows x 4 cols per thread) + x0-add epilogue, coalesced f4 stores
        {
            int rs = tid >> 4, cg = tid & 15;
            int t0 = 2 * rs, col = 4 * cg;
            float4 wv[12];               // ws rows t0..t0+11 at this col group
#pragma unroll
            for (int j = 0; j < 12; ++j)
                wv[j] = *(const float4*)&ws[(t0 + j) * WSS + col];
            float4 o0 = {0.f, 0.f, 0.f, 0.f}, o1 = {0.f, 0.f, 0.f, 0.f};
#pragma unroll
            for (int j = 0; j < FS; ++j) {
                if (j == HFS) continue;
                float kj = kh[j];
                o0.x = fmaf(kj, wv[j].x, o0.x);     o0.y = fmaf(kj, wv[j].y, o0.y);
                o0.z = fmaf(kj, wv[j].z, o0.z);     o0.w = fmaf(kj, wv[j].w, o0.w);
                o1.x = fmaf(kj, wv[j + 1].x, o1.x); o1.y = fmaf(kj, wv[j + 1].y, o1.y);
                o1.z = fmaf(kj, wv[j + 1].z, o1.z); o1.w = fmaf(kj, wv[j + 1].w, o1.w);
            }
            int gi = (b * Cn + c) * HWn + (h0 + t0) * Wn + (w0 + col);
            float4 xa = *(const float4*)(x0 + gi);
            float4 xc2 = *(const float4*)(x0 + gi + Wn);
            float4 ra = {xa.x + o0.x, xa.y + o0.y, xa.z + o0.z, xa.w + o0.w};
            float4 rb = {xc2.x + o1.x, xc2.y + o1.y, xc2.z + o1.z, xc2.w + o1.w};
            *(float4*)(xout + gi)      = ra;
            *(float4*)(xout + gi + Wn) = rb;
        }
        // no barrier here: next stage writes qs (phase A done at prior barrier),
        // reads srinv (read-only); the stage-end barrier orders phase B reads of ws
        // against next phase A writes.
    }
}

extern "C" void kernel_launch(void* const* d_in, const int* in_sizes, int n_in,
                              void* d_out, int out_size, void* d_ws, size_t ws_size,
                              hipStream_t stream) {
    const float* x0      = (const float*)d_in[0];
    const float* spacing = (const float*)d_in[1];
    const float* wgt     = (const float*)d_in[2];
    const float* itheta  = (const float*)d_in[3];
    float* out = (float*)d_out;

    float* A    = (float*)d_ws;          // ping-pong buffer (TOTn floats)
    float* taps = A + TOTn;

    k_taps<<<1, 256, 0, stream>>>(spacing, itheta, wgt, taps);

    dim3 g(Wn / TW, Hn / TH, Bn);        // 8 x 16 x 8 = 1024 blocks

    // double-buffered iterations: no kernel reads and writes the same tensor
    k_fused<<<g, 256, 0, stream>>>(x0,  x0, out, taps);   // it0
    k_fused<<<g, 256, 0, stream>>>(out, x0, A,   taps);   // it1
    k_fused<<<g, 256, 0, stream>>>(A,   x0, out, taps);   // it2
    k_fused<<<g, 256, 0, stream>>>(out, x0, A,   taps);   // it3
    k_fused<<<g, 256, 0, stream>>>(A,   x0, out, taps);   // it4
}

// Round 2
// 899.221 us; speedup vs baseline: 1.1886x; 1.0906x over previous
//
#include <hip/hip_runtime.h>

#define FS 11
#define HFS 5

constexpr int Bn = 8, Cn = 19, Hn = 512, Wn = 512;
constexpr int HWn = Hn * Wn;            // 262144
constexpr int CHWn = Cn * HWn;          // 4980736
constexpr int TOTn = Bn * CHWn;         // 39845888

// fused tile params
constexpr int TH = 32, TW = 64;
constexpr int HR  = TH + 10;            // 42 halo rows (h0-5 .. h0+36)
constexpr int HC4 = 20;                 // 80 halo cols = 20 float4 (w0-8 .. w0+71)
constexpr int NP4 = HR * HC4;           // 840 float4 halo pixels
constexpr int QS  = 84;                 // qs row stride; 84%32=20 -> staggered bank starts
constexpr int WSS = 68;                 // ws row stride; 68%32=4  -> staggered bank starts

// wave-uniform float -> SGPR
__device__ __forceinline__ float rfl(float x) {
    return __uint_as_float(__builtin_amdgcn_readfirstlane(__float_as_uint(x)));
}

// taps[b][dim][j]: dim0 = kh (H-direction), dim1 = kw (W-direction, scaled by weight)
__global__ void k_taps(const float* __restrict__ spacing,
                       const float* __restrict__ inv_theta,
                       const float* __restrict__ wgt,
                       float* __restrict__ taps) {
    int t = threadIdx.x;
    if (t < Bn * 2 * FS) {
        int j = t % FS;
        int dim = (t / FS) & 1;
        int b = t / (2 * FS);
        float d = spacing[b * 2 + dim] * (float)(j - HFS);
        float a = d * inv_theta[dim];
        float k = __expf(-0.5f * a * a);
        if (j == HFS) k = 0.0f;          // message passing excludes self
        if (dim == 1) k *= wgt[0];       // fold smoothness_weight into kw
        taps[t] = k;
    }
}

// One block = one (b, 32x64 tile), all 19 channels.
// softmax (no max-sub; bounded logits) + convW + convH + x0-add, fully fused.
// rinv (1/sum-exp) lives in REGISTERS (pass1 and stage share the thread->pixel map).
// x[c+1] and x0 epilogue values are register-prefetched so no global latency sits
// in front of a barrier inside the channel loop.
__global__ __launch_bounds__(256, 4) void k_fused(const float* __restrict__ xin,
                                                  const float* __restrict__ x0,
                                                  float* __restrict__ xout,
                                                  const float* __restrict__ taps) {
    __shared__ float qs[HR * QS];        // 14112 B
    __shared__ float ws[HR * WSS];       // 11424 B  (total 25536 B)

    const int tid = threadIdx.x;
    const int w0 = blockIdx.x * TW;
    const int h0 = blockIdx.y * TH;
    const int b  = blockIdx.z;

    const float* tp = taps + b * (2 * FS);
    float kh[FS], kw[FS];
#pragma unroll
    for (int j = 0; j < FS; j++) { kh[j] = rfl(tp[j]); kw[j] = rfl(tp[FS + j]); }

    const float* xb = xin + b * CHWn;

    // ---- per-thread halo items (same mapping reused by pass1 and every stage) ----
    int off[4], lo[4];
    bool act[4], it[4];
#pragma unroll
    for (int k = 0; k < 4; k++) {
        int i = tid + 256 * k;
        it[k] = (i < NP4);
        int r = i / HC4, c4 = i % HC4;
        int hh = h0 - 5 + r;
        int ww = w0 - 8 + 4 * c4;
        act[k] = it[k] && hh >= 0 && hh < Hn && ww >= 0 && ww <= Wn - 4;
        off[k] = hh * Wn + ww;
        lo[k]  = r * QS + 4 * c4;
    }

    // ---- pass 1: rinv = 1/sum_c exp(x_c) per halo pixel, kept in registers;
    //      channel 0's raw x retained in px (free prefetch for stage 0) ----
    float4 px[4], rinv[4];
    {
        float4 s[4];
#pragma unroll
        for (int k = 0; k < 4; k++) {
            s[k] = make_float4(0.f, 0.f, 0.f, 0.f);
            if (act[k]) {
                float4 v = *(const float4*)(xb + off[k]);
                px[k] = v;
                s[k].x = __expf(v.x); s[k].y = __expf(v.y);
                s[k].z = __expf(v.z); s[k].w = __expf(v.w);
            }
        }
#pragma unroll 2
        for (int c = 1; c < Cn; ++c) {
#pragma unroll
            for (int k = 0; k < 4; k++) {
                if (!act[k]) continue;
                float4 v = *(const float4*)(xb + c * HWn + off[k]);
                s[k].x += __expf(v.x); s[k].y += __expf(v.y);
                s[k].z += __expf(v.z); s[k].w += __expf(v.w);
            }
        }
#pragma unroll
        for (int k = 0; k < 4; k++)
            if (act[k])
                rinv[k] = make_float4(1.f / s[k].x, 1.f / s[k].y,
                                      1.f / s[k].z, 1.f / s[k].w);
    }

    const int t0  = 2 * (tid >> 4);      // phase-B output rows t0, t0+1
    const int col = 4 * (tid & 15);      // phase-B output cols col..col+3
    const int pix = (h0 + t0) * Wn + (w0 + col);

    // ---- channel loop: stage(q from regs) | convW | convH + epilogue ----
    for (int c = 0; c < Cn; ++c) {
        // stage: qs = exp(x_c) * rinv  (zeros outside image = zero-pad semantics)
#pragma unroll
        for (int k = 0; k < 4; k++) {
            if (!it[k]) continue;
            float4 qv = make_float4(0.f, 0.f, 0.f, 0.f);
            if (act[k]) {
                qv.x = __expf(px[k].x) * rinv[k].x;
                qv.y = __expf(px[k].y) * rinv[k].y;
                qv.z = __expf(px[k].z) * rinv[k].z;
                qv.w = __expf(px[k].w) * rinv[k].w;
            }
            *(float4*)&qs[lo[k]] = qv;
        }
        __syncthreads();

        // issue prefetches: next channel's x (for next stage) + this channel's x0
        if (c + 1 < Cn) {
#pragma unroll
            for (int k = 0; k < 4; k++)
                if (act[k]) px[k] = *(const float4*)(xb + (c + 1) * HWn + off[k]);
        }
        const int gi = (b * Cn + c) * HWn + pix;
        float4 xA = *(const float4*)(x0 + gi);
        float4 xB = *(const float4*)(x0 + gi + Wn);

        // phase A: convW for all 42 halo rows; task = (row r, 8-col group g)
#pragma unroll 1
        for (int i2 = tid; i2 < HR * 8; i2 += 256) {
            int r = i2 >> 3, g = i2 & 7;
            float t[24];
#pragma unroll
            for (int m = 0; m < 6; ++m)
                *(float4*)&t[4 * m] = *(const float4*)&qs[r * QS + 8 * g + 4 * m];
            float o[8];
#pragma unroll
            for (int k2 = 0; k2 < 8; ++k2) {
                float a = 0.f;
#pragma unroll
                for (int j = 0; j < FS; ++j) {
                    if (j == HFS) continue;     // center tap zero
                    a = fmaf(kw[j], t[k2 + 3 + j], a);
                }
                o[k2] = a;
            }
            float4 oa = {o[0], o[1], o[2], o[3]};
            float4 ob = {o[4], o[5], o[6], o[7]};
            *(float4*)&ws[r * WSS + 8 * g]     = oa;
            *(float4*)&ws[r * WSS + 8 * g + 4] = ob;
        }
        __syncthreads();

        // phase B: convH (2 rows x 4 cols per thread) + x0-add, coalesced f4 stores
        {
            float4 wv[12];
#pragma unroll
            for (int j = 0; j < 12; ++j)
                wv[j] = *(const float4*)&ws[(t0 + j) * WSS + col];
            float4 o0 = {0.f, 0.f, 0.f, 0.f}, o1 = {0.f, 0.f, 0.f, 0.f};
#pragma unroll
            for (int j = 0; j < FS; ++j) {
                if (j == HFS) continue;
                float kj = kh[j];
                o0.x = fmaf(kj, wv[j].x, o0.x);     o0.y = fmaf(kj, wv[j].y, o0.y);
                o0.z = fmaf(kj, wv[j].z, o0.z);     o0.w = fmaf(kj, wv[j].w, o0.w);
                o1.x = fmaf(kj, wv[j + 1].x, o1.x); o1.y = fmaf(kj, wv[j + 1].y, o1.y);
                o1.z = fmaf(kj, wv[j + 1].z, o1.z); o1.w = fmaf(kj, wv[j + 1].w, o1.w);
            }
            float4 ra = {xA.x + o0.x, xA.y + o0.y, xA.z + o0.z, xA.w + o0.w};
            float4 rb = {xB.x + o1.x, xB.y + o1.y, xB.z + o1.z, xB.w + o1.w};
            *(float4*)(xout + gi)      = ra;
            *(float4*)(xout + gi + Wn) = rb;
        }
        // no 3rd barrier: B reads ws; next A writes ws only after next stage's barrier
    }
}

extern "C" void kernel_launch(void* const* d_in, const int* in_sizes, int n_in,
                              void* d_out, int out_size, void* d_ws, size_t ws_size,
                              hipStream_t stream) {
    const float* x0      = (const float*)d_in[0];
    const float* spacing = (const float*)d_in[1];
    const float* wgt     = (const float*)d_in[2];
    const float* itheta  = (const float*)d_in[3];
    float* out = (float*)d_out;

    float* A    = (float*)d_ws;          // ping-pong buffer (TOTn floats)
    float* taps = A + TOTn;

    k_taps<<<1, 256, 0, stream>>>(spacing, itheta, wgt, taps);

    dim3 g(Wn / TW, Hn / TH, Bn);        // 8 x 16 x 8 = 1024 blocks (exactly 4/CU)

    // double-buffered iterations: no kernel reads and writes the same tensor
    k_fused<<<g, 256, 0, stream>>>(x0,  x0, out, taps);   // it0
    k_fused<<<g, 256, 0, stream>>>(out, x0, A,   taps);   // it1
    k_fused<<<g, 256, 0, stream>>>(A,   x0, out, taps);   // it2
    k_fused<<<g, 256, 0, stream>>>(out, x0, A,   taps);   // it3
    k_fused<<<g, 256, 0, stream>>>(A,   x0, out, taps);   // it4
}